// Round 8
// baseline (97.649 us; speedup 1.0000x reference)
//
#include <hip/hip_runtime.h>

// out = sign(x) * F(|x|);  F = 16-step spiking recurrence.
// Divide by (|v|+1) > 0 never changes sign -> z_t = (v_t > T_t).
// Interval analysis proves z=1 always at t = 0,2,3,6,11,13 (margins >= 0.5).
//
//  - v-chain: BIT-EXACT to numpy reference (each update = one IEEE fl op
//    identical to reference's v - z*h). Packed fp32 fma is IEEE per half.
//  - acc-chain: reorderable (verified absmax 0.0 in R5/R6). Unconditional d's
//    folded into C0 = 1.21686509; 10 conditional fmas remain.
//
// R8 experiment: REMOVE nontemporal store (single-variable A/B vs R7).
// NT entered bundled in R3 and never changed FETCH/WRITE; hypothesis is its
// evict-first policy degrades L2 write-combining (4.8 TB/s observed vs
// 6.3 TB/s copy ceiling). Everything else identical to R7.

typedef float  vf2 __attribute__((ext_vector_type(2)));
typedef unsigned int vu2 __attribute__((ext_vector_type(2)));
typedef float  vfloat4 __attribute__((ext_vector_type(4)));

__device__ __forceinline__ vf2 splat2(float s) { vf2 r; r.x = s; r.y = s; return r; }

__device__ __forceinline__ vf2 run16x2(vf2 xv) {
    vf2 v = __builtin_elementwise_abs(xv);
    vf2 z1, z4, z5, z7, z8, z9, z10, z12, z14, z15;

    // ---- v-chain + decisions (bit-exact, reference order) ----
    v = v - splat2(0.06285988f);                                   // t=1
    z1.x = (v.x > 1.2887092f) ? 1.0f : 0.0f;
    z1.y = (v.y > 1.2887092f) ? 1.0f : 0.0f;
    v = __builtin_elementwise_fma(z1, splat2(-0.26102483f), v);    // t=2 (z=1 always)
    v = v + splat2(0.37457255f);                                   // t=3 (always, h<0)
    v = v - splat2(0.3718868f);                                    // t=4
    z4.x = (v.x > 1.1932085f) ? 1.0f : 0.0f;
    z4.y = (v.y > 1.1932085f) ? 1.0f : 0.0f;
    v = __builtin_elementwise_fma(z4, splat2(-0.37248886f), v);    // t=5
    z5.x = (v.x > 2.9062123f) ? 1.0f : 0.0f;
    z5.y = (v.y > 2.9062123f) ? 1.0f : 0.0f;
    v = __builtin_elementwise_fma(z5, splat2(-0.63687307f), v);    // t=6 (always)
    v = v + splat2(0.92578804f);                                   // t=7 (h<0)
    z7.x = (v.x > 1.9449068f) ? 1.0f : 0.0f;
    z7.y = (v.y > 1.9449068f) ? 1.0f : 0.0f;
    v = __builtin_elementwise_fma(z7, splat2(-1.9272704f), v);     // t=8
    z8.x = (v.x > 0.6202121f) ? 1.0f : 0.0f;
    z8.y = (v.y > 0.6202121f) ? 1.0f : 0.0f;
    v = __builtin_elementwise_fma(z8, splat2(-0.7057378f), v);     // t=9
    z9.x = (v.x > 0.41550368f) ? 1.0f : 0.0f;
    z9.y = (v.y > 0.41550368f) ? 1.0f : 0.0f;
    v = __builtin_elementwise_fma(z9, splat2(-0.33205885f), v);    // t=10
    z10.x = (v.x > 0.6942196f) ? 1.0f : 0.0f;
    z10.y = (v.y > 0.6942196f) ? 1.0f : 0.0f;
    v = __builtin_elementwise_fma(z10, splat2(-1.1465814f), v);    // t=11 (always)
    v = v + splat2(1.2022963f);                                    // t=12 (h<0)
    z12.x = (v.x > 2.0298457f) ? 1.0f : 0.0f;
    z12.y = (v.y > 2.0298457f) ? 1.0f : 0.0f;
    v = __builtin_elementwise_fma(z12, splat2(-1.5285196f), v);    // t=13 (always)
    v = v - splat2(0.6882014f);                                    // t=14
    z14.x = (v.x > 1.0268241f) ? 1.0f : 0.0f;
    z14.y = (v.y > 1.0268241f) ? 1.0f : 0.0f;
    v = __builtin_elementwise_fma(z14, splat2(-1.6742821f), v);    // t=15
    z15.x = (v.x > 0.6855806f) ? 1.0f : 0.0f;
    z15.y = (v.y > 0.6855806f) ? 1.0f : 0.0f;

    // ---- acc-chain (reorderable): C0 = d0+d2+d3+d6+d11+d13 ----
    vf2 acc = splat2(1.21686509f);
    acc = __builtin_elementwise_fma(z1,  splat2(-0.15619771f), acc);
    acc = __builtin_elementwise_fma(z4,  splat2(-0.17966147f), acc);
    acc = __builtin_elementwise_fma(z5,  splat2(-0.05126573f), acc);
    acc = __builtin_elementwise_fma(z7,  splat2(-0.3483371f),  acc);
    acc = __builtin_elementwise_fma(z8,  splat2(-0.12764367f), acc);
    acc = __builtin_elementwise_fma(z9,  splat2(-0.05997599f), acc);
    acc = __builtin_elementwise_fma(z10, splat2(-0.06374894f), acc);
    acc = __builtin_elementwise_fma(z12, splat2(-0.05318592f), acc);
    acc = __builtin_elementwise_fma(z14, splat2(-0.03889612f), acc);
    acc = __builtin_elementwise_fma(z15, splat2(-0.02578991f), acc);

    // acc * sign(x): xor sign bit; force 0 when x == +/-0
    vu2 sb = __builtin_bit_cast(vu2, xv);
    sb = sb & 0x80000000u;
    vf2 r = __builtin_bit_cast(vf2, __builtin_bit_cast(vu2, acc) ^ sb);
    r.x = (xv.x == 0.0f) ? 0.0f : r.x;
    r.y = (xv.y == 0.0f) ? 0.0f : r.y;
    return r;
}

// Scalar path for the guarded fallback/tail.
__device__ __forceinline__ float run16(float xval) {
    vf2 p; p.x = xval; p.y = xval;
    return run16x2(p).x;
}

// One-shot kernel: each block owns a contiguous 1024-float4 (16 KB) chunk;
// thread t does 4 coalesced float4s at base + t + k*256.
__global__ __launch_bounds__(256) void spike_oneshot(
    const float* __restrict__ x, float* __restrict__ out)
{
    const vfloat4* __restrict__ x4 = (const vfloat4*)x;
    vfloat4* __restrict__ o4 = (vfloat4*)out;

    const int base = blockIdx.x * 1024 + threadIdx.x;

    vfloat4 in[4];
#pragma unroll
    for (int k = 0; k < 4; ++k) in[k] = x4[base + k * 256];
#pragma unroll
    for (int k = 0; k < 4; ++k) {
        vf2 lo, hi;
        lo.x = in[k].x; lo.y = in[k].y;
        hi.x = in[k].z; hi.y = in[k].w;
        vf2 rlo = run16x2(lo);
        vf2 rhi = run16x2(hi);
        vfloat4 r;
        r.x = rlo.x; r.y = rlo.y; r.z = rhi.x; r.w = rhi.y;
        o4[base + k * 256] = r;   // plain store (A/B vs R7's nontemporal)
    }
}

// Guarded grid-stride fallback for arbitrary n.
__global__ __launch_bounds__(256) void spike_guarded(
    const float* __restrict__ x, float* __restrict__ out, int n4, int n)
{
    const vfloat4* __restrict__ x4 = (const vfloat4*)x;
    vfloat4* __restrict__ o4 = (vfloat4*)out;

    const int tid = blockIdx.x * blockDim.x + threadIdx.x;
    const int stride = gridDim.x * blockDim.x;

    for (int i = tid; i < n4; i += stride) {
        vfloat4 in = x4[i];
        vf2 lo, hi;
        lo.x = in.x; lo.y = in.y;
        hi.x = in.z; hi.y = in.w;
        vf2 rlo = run16x2(lo);
        vf2 rhi = run16x2(hi);
        vfloat4 r;
        r.x = rlo.x; r.y = rlo.y; r.z = rhi.x; r.w = rhi.y;
        o4[i] = r;
    }
    const int tail_start = n4 * 4;
    for (int i = tail_start + tid; i < n; i += stride) {
        out[i] = run16(x[i]);
    }
}

extern "C" void kernel_launch(void* const* d_in, const int* in_sizes, int n_in,
                              void* d_out, int out_size, void* d_ws, size_t ws_size,
                              hipStream_t stream) {
    const float* x = (const float*)d_in[0];
    float* out = (float*)d_out;

    const int n = in_sizes[0];
    const int n4 = n / 4;

    if ((n % 4) == 0 && (n4 % 1024) == 0) {
        // Bench shape: n4 = 2^24 -> 16384 one-shot blocks.
        const int blocks = n4 / 1024;
        spike_oneshot<<<blocks, 256, 0, stream>>>(x, out);
    } else {
        int blocks = 2048;
        int need = (n4 + 255) / 256;
        if (need < blocks) blocks = (need > 0) ? need : 1;
        spike_guarded<<<blocks, 256, 0, stream>>>(x, out, n4, n);
    }
}

// Round 9
// 82.282 us; speedup vs baseline: 1.1868x; 1.1868x over previous
//
#include <hip/hip_runtime.h>

// out = sign(x) * F(|x|);  F = 16-step spiking recurrence.
// Divide by (|v|+1) > 0 never changes sign -> z_t = (v_t > T_t).
// Interval analysis proves z=1 always at t = 0,2,3,6,11,13 (margins >= 0.5).
//
//  - v-chain: BIT-EXACT to numpy reference (each update = one IEEE fl op
//    identical to reference's v - z*h). Packed fp32 fma is IEEE per half.
//  - acc-chain: reorderable (verified absmax 0.0 in R5/R6). Unconditional d's
//    folded into C0 = 1.21686509; 10 conditional fmas remain.
//
// Final structure (R7, restored after R8 A/B):
//  - one-shot grid: 16384 blocks x 256 thr, each block owns a contiguous
//    16 KB chunk (4 coalesced float4/thread) -> block churn pipelines memory.
//  - NONTEMPORAL stores: proven +15% by R8 ablation (plain stores thrash
//    L2/L3 with the write stream and evict the retained input half).
//  - element-pair (<2 x float>) math for packed fp32 VALU where available.
// At 82.5 us this sits at ~101% of the copy-equivalent ceiling
// (524 MB data motion / 6.29 TB/s measured copy BW = 83.3 us) -> roofline.

typedef float  vf2 __attribute__((ext_vector_type(2)));
typedef unsigned int vu2 __attribute__((ext_vector_type(2)));
typedef float  vfloat4 __attribute__((ext_vector_type(4)));

__device__ __forceinline__ vf2 splat2(float s) { vf2 r; r.x = s; r.y = s; return r; }

__device__ __forceinline__ vf2 run16x2(vf2 xv) {
    vf2 v = __builtin_elementwise_abs(xv);
    vf2 z1, z4, z5, z7, z8, z9, z10, z12, z14, z15;

    // ---- v-chain + decisions (bit-exact, reference order) ----
    v = v - splat2(0.06285988f);                                   // t=1
    z1.x = (v.x > 1.2887092f) ? 1.0f : 0.0f;
    z1.y = (v.y > 1.2887092f) ? 1.0f : 0.0f;
    v = __builtin_elementwise_fma(z1, splat2(-0.26102483f), v);    // t=2 (z=1 always)
    v = v + splat2(0.37457255f);                                   // t=3 (always, h<0)
    v = v - splat2(0.3718868f);                                    // t=4
    z4.x = (v.x > 1.1932085f) ? 1.0f : 0.0f;
    z4.y = (v.y > 1.1932085f) ? 1.0f : 0.0f;
    v = __builtin_elementwise_fma(z4, splat2(-0.37248886f), v);    // t=5
    z5.x = (v.x > 2.9062123f) ? 1.0f : 0.0f;
    z5.y = (v.y > 2.9062123f) ? 1.0f : 0.0f;
    v = __builtin_elementwise_fma(z5, splat2(-0.63687307f), v);    // t=6 (always)
    v = v + splat2(0.92578804f);                                   // t=7 (h<0)
    z7.x = (v.x > 1.9449068f) ? 1.0f : 0.0f;
    z7.y = (v.y > 1.9449068f) ? 1.0f : 0.0f;
    v = __builtin_elementwise_fma(z7, splat2(-1.9272704f), v);     // t=8
    z8.x = (v.x > 0.6202121f) ? 1.0f : 0.0f;
    z8.y = (v.y > 0.6202121f) ? 1.0f : 0.0f;
    v = __builtin_elementwise_fma(z8, splat2(-0.7057378f), v);     // t=9
    z9.x = (v.x > 0.41550368f) ? 1.0f : 0.0f;
    z9.y = (v.y > 0.41550368f) ? 1.0f : 0.0f;
    v = __builtin_elementwise_fma(z9, splat2(-0.33205885f), v);    // t=10
    z10.x = (v.x > 0.6942196f) ? 1.0f : 0.0f;
    z10.y = (v.y > 0.6942196f) ? 1.0f : 0.0f;
    v = __builtin_elementwise_fma(z10, splat2(-1.1465814f), v);    // t=11 (always)
    v = v + splat2(1.2022963f);                                    // t=12 (h<0)
    z12.x = (v.x > 2.0298457f) ? 1.0f : 0.0f;
    z12.y = (v.y > 2.0298457f) ? 1.0f : 0.0f;
    v = __builtin_elementwise_fma(z12, splat2(-1.5285196f), v);    // t=13 (always)
    v = v - splat2(0.6882014f);                                    // t=14
    z14.x = (v.x > 1.0268241f) ? 1.0f : 0.0f;
    z14.y = (v.y > 1.0268241f) ? 1.0f : 0.0f;
    v = __builtin_elementwise_fma(z14, splat2(-1.6742821f), v);    // t=15
    z15.x = (v.x > 0.6855806f) ? 1.0f : 0.0f;
    z15.y = (v.y > 0.6855806f) ? 1.0f : 0.0f;

    // ---- acc-chain (reorderable): C0 = d0+d2+d3+d6+d11+d13 ----
    vf2 acc = splat2(1.21686509f);
    acc = __builtin_elementwise_fma(z1,  splat2(-0.15619771f), acc);
    acc = __builtin_elementwise_fma(z4,  splat2(-0.17966147f), acc);
    acc = __builtin_elementwise_fma(z5,  splat2(-0.05126573f), acc);
    acc = __builtin_elementwise_fma(z7,  splat2(-0.3483371f),  acc);
    acc = __builtin_elementwise_fma(z8,  splat2(-0.12764367f), acc);
    acc = __builtin_elementwise_fma(z9,  splat2(-0.05997599f), acc);
    acc = __builtin_elementwise_fma(z10, splat2(-0.06374894f), acc);
    acc = __builtin_elementwise_fma(z12, splat2(-0.05318592f), acc);
    acc = __builtin_elementwise_fma(z14, splat2(-0.03889612f), acc);
    acc = __builtin_elementwise_fma(z15, splat2(-0.02578991f), acc);

    // acc * sign(x): xor sign bit; force 0 when x == +/-0
    vu2 sb = __builtin_bit_cast(vu2, xv);
    sb = sb & 0x80000000u;
    vf2 r = __builtin_bit_cast(vf2, __builtin_bit_cast(vu2, acc) ^ sb);
    r.x = (xv.x == 0.0f) ? 0.0f : r.x;
    r.y = (xv.y == 0.0f) ? 0.0f : r.y;
    return r;
}

// Scalar path for the guarded fallback/tail.
__device__ __forceinline__ float run16(float xval) {
    vf2 p; p.x = xval; p.y = xval;
    return run16x2(p).x;
}

// One-shot kernel: each block owns a contiguous 1024-float4 (16 KB) chunk;
// thread t does 4 coalesced float4s at base + t + k*256.
__global__ __launch_bounds__(256) void spike_oneshot(
    const float* __restrict__ x, float* __restrict__ out)
{
    const vfloat4* __restrict__ x4 = (const vfloat4*)x;
    vfloat4* __restrict__ o4 = (vfloat4*)out;

    const int base = blockIdx.x * 1024 + threadIdx.x;

    vfloat4 in[4];
#pragma unroll
    for (int k = 0; k < 4; ++k) in[k] = x4[base + k * 256];
#pragma unroll
    for (int k = 0; k < 4; ++k) {
        vf2 lo, hi;
        lo.x = in[k].x; lo.y = in[k].y;
        hi.x = in[k].z; hi.y = in[k].w;
        vf2 rlo = run16x2(lo);
        vf2 rhi = run16x2(hi);
        vfloat4 r;
        r.x = rlo.x; r.y = rlo.y; r.z = rhi.x; r.w = rhi.y;
        __builtin_nontemporal_store(r, &o4[base + k * 256]);  // NT: +15% (R8 A/B)
    }
}

// Guarded grid-stride fallback for arbitrary n.
__global__ __launch_bounds__(256) void spike_guarded(
    const float* __restrict__ x, float* __restrict__ out, int n4, int n)
{
    const vfloat4* __restrict__ x4 = (const vfloat4*)x;
    vfloat4* __restrict__ o4 = (vfloat4*)out;

    const int tid = blockIdx.x * blockDim.x + threadIdx.x;
    const int stride = gridDim.x * blockDim.x;

    for (int i = tid; i < n4; i += stride) {
        vfloat4 in = x4[i];
        vf2 lo, hi;
        lo.x = in.x; lo.y = in.y;
        hi.x = in.z; hi.y = in.w;
        vf2 rlo = run16x2(lo);
        vf2 rhi = run16x2(hi);
        vfloat4 r;
        r.x = rlo.x; r.y = rlo.y; r.z = rhi.x; r.w = rhi.y;
        __builtin_nontemporal_store(r, &o4[i]);
    }
    const int tail_start = n4 * 4;
    for (int i = tail_start + tid; i < n; i += stride) {
        out[i] = run16(x[i]);
    }
}

extern "C" void kernel_launch(void* const* d_in, const int* in_sizes, int n_in,
                              void* d_out, int out_size, void* d_ws, size_t ws_size,
                              hipStream_t stream) {
    const float* x = (const float*)d_in[0];
    float* out = (float*)d_out;

    const int n = in_sizes[0];
    const int n4 = n / 4;

    if ((n % 4) == 0 && (n4 % 1024) == 0) {
        // Bench shape: n4 = 2^24 -> 16384 one-shot blocks.
        const int blocks = n4 / 1024;
        spike_oneshot<<<blocks, 256, 0, stream>>>(x, out);
    } else {
        int blocks = 2048;
        int need = (n4 + 255) / 256;
        if (need < blocks) blocks = (need > 0) ? need : 1;
        spike_guarded<<<blocks, 256, 0, stream>>>(x, out, n4, n);
    }
}